// Round 11
// baseline (1391.187 us; speedup 1.0000x reference)
//
#include <hip/hip_runtime.h>

#define S_ 2048
#define D_ 64
#define H_ 12
#define TQB 16          // queries per block
#define CK 128          // keys per chunk (4 waves x 32 keys)
#define NCH (S_/CK)     // 16 chunks

typedef __attribute__((ext_vector_type(8))) short bf16x8;
typedef __attribute__((ext_vector_type(4))) float f32x4;

__device__ __forceinline__ unsigned short f2bf(float x) {
    unsigned u = __float_as_uint(x);
    return (unsigned short)((u + 0x7FFFu + ((u >> 16) & 1u)) >> 16);   // RNE
}

// Stage 128 keys x 64 d (f32 global, coalesced) -> bf16 LDS, XOR-swizzled
// rows (idx ^= (key&7)<<3 in shorts) so 16-lane column reads are conflict-free.
#define STAGE(dst, srcp) {                                                  \
    const int key_ = tid >> 1, hf_ = tid & 1;                               \
    const float4* gp_ = (const float4*)((srcp) + (size_t)key_ * D_) + hf_*8;\
    float4 f_[8];                                                           \
    _Pragma("unroll") for (int i_ = 0; i_ < 8; ++i_) f_[i_] = gp_[i_];      \
    _Pragma("unroll") for (int g_ = 0; g_ < 4; ++g_) {                      \
        bf16x8 o_;                                                          \
        _Pragma("unroll") for (int e_ = 0; e_ < 8; ++e_)                    \
            o_[e_] = (short)f2bf(((const float*)f_)[g_*8 + e_]);            \
        int idx_ = (key_*64 + hf_*32 + g_*8) ^ ((key_ & 7) << 3);           \
        *(bf16x8*)&dst[idx_] = o_;                                          \
    } }

// ONE-PASS, ZERO-FIXUP: per chunk QK^T (mfma) + bias + exp; e kept packed
// bf16x2 in registers (epk[16][2][2], 64 VGPRs, ALL indices compile-time
// static via full unroll -> no scratch). After row sums: attn = bf16(e)*inv
// stored nt (no separate normalization kernel; saves 806MB HBM round trip).
// PV accumulates unnormalized, rescaled in epilogue. C/D layout per m89:
// col=lane&15, row=(lane>>4)*4+reg.
__global__ __launch_bounds__(256, 3) void sdpa_bias_kernel(
    const float* __restrict__ qm, const float* __restrict__ km,
    const float* __restrict__ vm, const int* __restrict__ mask,
    const float* __restrict__ bias, float* __restrict__ out,
    float* __restrict__ attn)
{
    const int tid  = threadIdx.x;
    const int lane = tid & 63;
    const int w    = tid >> 6;
    const int col  = lane & 15;     // MFMA col (B) / row (A) index
    const int lg   = lane >> 4;     // lane group 0..3

    const int bhp = blockIdx.y;     // h-major pairing for bias L3 reuse
    const int h = bhp >> 1, b = bhp & 1;
    const int bh = b * H_ + h;
    const int q0 = blockIdx.x * TQB;

    __shared__ __align__(16) short qs_s[TQB * D_];     // 2 KB
    __shared__ __align__(16) short ks_s[CK * D_];      // 16 KB
    __shared__ __align__(16) short vs_s[CK * D_];      // 16 KB
    __shared__ __align__(16) short ps_s[4 * TQB * 40]; // 5 KB (row stride 40)
    __shared__ float sums_s[4][TQB];
    __shared__ float invs_s[TQB];

    // ---- stage Q (x 1/T, bf16, swizzled) ----
    if (tid < 64) {
        int row = tid >> 2, c4 = tid & 3;
        const float4* qp = (const float4*)(qm + ((size_t)bh * S_ + q0 + row) * D_) + c4*4;
        float4 f[4];
        #pragma unroll
        for (int i = 0; i < 4; ++i) f[i] = qp[i];
        #pragma unroll
        for (int g = 0; g < 2; ++g) {
            bf16x8 o;
            #pragma unroll
            for (int e = 0; e < 8; ++e)
                o[e] = (short)f2bf(((const float*)f)[g*8 + e] * 0.125f);
            int idx = (row*64 + c4*16 + g*8) ^ ((row & 7) << 3);
            *(bf16x8*)&qs_s[idx] = o;
        }
    }
    __syncthreads();

    // A-frags of Q (chunk-invariant): row=col, d = lg*8+e (+32 for hi half)
    bf16x8 qa0 = *(const bf16x8*)&qs_s[(col*64 +  0 + lg*8) ^ ((col & 7) << 3)];
    bf16x8 qa1 = *(const bf16x8*)&qs_s[(col*64 + 32 + lg*8) ^ ((col & 7) << 3)];

    const int*   mp = mask + (size_t)b * S_;
    const float* bb = bias + (size_t)h * S_ * S_;
    const float* kbase = km + (size_t)bh * S_ * D_;
    const float* vbase = vm + (size_t)bh * S_ * D_;

    // ========== single pass: sums + PV; e history packed in registers ==========
    f32x4 oacc[4];
    #pragma unroll
    for (int d = 0; d < 4; ++d) oacc[d] = (f32x4){0.f, 0.f, 0.f, 0.f};
    float srow[4] = {0.f, 0.f, 0.f, 0.f};
    unsigned epk[NCH][2][2];            // bf16x2-packed e; static idx only
    short* psw = &ps_s[w * TQB * 40];

    #pragma unroll
    for (int ch = 0; ch < NCH; ++ch) {
        __syncthreads();
        STAGE(ks_s, kbase + (size_t)ch * CK * D_);
        STAGE(vs_s, vbase + (size_t)ch * CK * D_);
        __syncthreads();
        #pragma unroll
        for (int sub = 0; sub < 2; ++sub) {
            int kl = w*32 + sub*16 + col;
            int gk = ch*CK + kl;
            bf16x8 b0 = *(const bf16x8*)&ks_s[(kl*64 +  0 + lg*8) ^ ((kl & 7) << 3)];
            bf16x8 b1 = *(const bf16x8*)&ks_s[(kl*64 + 32 + lg*8) ^ ((kl & 7) << 3)];
            f32x4 c = {0.f, 0.f, 0.f, 0.f};
            c = __builtin_amdgcn_mfma_f32_16x16x32_bf16(qa0, b0, c, 0, 0, 0);
            c = __builtin_amdgcn_mfma_f32_16x16x32_bf16(qa1, b1, c, 0, 0, 0);
            int m = mp[gk];
            unsigned short us[4];
            #pragma unroll
            for (int i = 0; i < 4; ++i) {
                int row = lg*4 + i;
                float lv = c[i] + __builtin_nontemporal_load(bb + (size_t)(q0+row)*S_ + gk);
                float e = m ? __expf(lv) : 0.f;
                us[i] = f2bf(e);
                psw[row*40 + sub*16 + col] = (short)us[i];   // PV fragment
                srow[i] += e;
            }
            epk[ch][sub][0] = (unsigned)us[0] | ((unsigned)us[1] << 16);
            epk[ch][sub][1] = (unsigned)us[2] | ((unsigned)us[3] << 16);
        }
        // PV: this wave's 16q x 32keys tile (A=P from psw, B=V from vs_s).
        bf16x8 pa = *(const bf16x8*)&psw[col*40 + lg*8];
        #pragma unroll
        for (int dt = 0; dt < 4; ++dt) {
            bf16x8 vb;
            #pragma unroll
            for (int e = 0; e < 8; ++e) {
                int key = w*32 + lg*8 + e;
                vb[e] = vs_s[(key*64 + dt*16 + col) ^ ((key & 7) << 3)];
            }
            oacc[dt] = __builtin_amdgcn_mfma_f32_16x16x32_bf16(pa, vb, oacc[dt], 0, 0, 0);
        }
    }

    // ---- row sums -> inv ----
    #pragma unroll
    for (int i = 0; i < 4; ++i) {
        float t = srow[i];
        t += __shfl_xor(t, 1, 64); t += __shfl_xor(t, 2, 64);
        t += __shfl_xor(t, 4, 64); t += __shfl_xor(t, 8, 64);
        srow[i] = t;
    }
    if (col == 0) {
        #pragma unroll
        for (int i = 0; i < 4; ++i) sums_s[w][lg*4 + i] = srow[i];
    }
    __syncthreads();
    if (tid < TQB)
        invs_s[tid] = 1.f / (sums_s[0][tid] + sums_s[1][tid]
                           + sums_s[2][tid] + sums_s[3][tid]);
    __syncthreads();
    float inv[4];
    #pragma unroll
    for (int i = 0; i < 4; ++i) inv[i] = invs_s[lg*4 + i];

    // ---- normalized attn stores from register history ----
    float* arow = attn + ((size_t)bh * S_ + q0) * S_;
    #pragma unroll
    for (int ch = 0; ch < NCH; ++ch) {
        #pragma unroll
        for (int sub = 0; sub < 2; ++sub) {
            int gk = ch*CK + w*32 + sub*16 + col;
            unsigned u0 = epk[ch][sub][0], u1 = epk[ch][sub][1];
            __builtin_nontemporal_store(__uint_as_float(u0 << 16)         * inv[0],
                                        arow + (size_t)(lg*4 + 0) * S_ + gk);
            __builtin_nontemporal_store(__uint_as_float(u0 & 0xFFFF0000u) * inv[1],
                                        arow + (size_t)(lg*4 + 1) * S_ + gk);
            __builtin_nontemporal_store(__uint_as_float(u1 << 16)         * inv[2],
                                        arow + (size_t)(lg*4 + 2) * S_ + gk);
            __builtin_nontemporal_store(__uint_as_float(u1 & 0xFFFF0000u) * inv[3],
                                        arow + (size_t)(lg*4 + 3) * S_ + gk);
        }
    }

    // ---- cross-wave PV reduce (reuse ks_s as f32[4][16][64]) ----
    float* ob = (float*)ks_s;
    #pragma unroll
    for (int dt = 0; dt < 4; ++dt)
        #pragma unroll
        for (int i = 0; i < 4; ++i)
            ob[w*1024 + (lg*4 + i)*64 + dt*16 + col] = oacc[dt][i];
    __syncthreads();
    float* op = out + ((size_t)bh * S_ + q0) * D_;
    for (int id = tid; id < TQB * D_; id += 256) {
        int q = id >> 6, d = id & 63;
        op[(size_t)q * D_ + d] = (ob[q*64 + d] + ob[1024 + q*64 + d]
                                + ob[2048 + q*64 + d] + ob[3072 + q*64 + d]) * invs_s[q];
    }
}

extern "C" void kernel_launch(void* const* d_in, const int* in_sizes, int n_in,
                              void* d_out, int out_size, void* d_ws, size_t ws_size,
                              hipStream_t stream) {
    const float* q    = (const float*)d_in[0];
    const float* k    = (const float*)d_in[1];
    const float* v    = (const float*)d_in[2];
    const int*   mask = (const int*)d_in[3];
    const float* bias = (const float*)d_in[4];
    float* out  = (float*)d_out;
    float* attn = out + (size_t)2 * H_ * S_ * D_;   // B*H*S*D elements, then attn

    dim3 grid(S_ / TQB, 2 * H_);
    sdpa_bias_kernel<<<grid, 256, 0, stream>>>(q, k, v, mask, bias, out, attn);
}